// Round 1
// baseline (311.520 us; speedup 1.0000x reference)
//
#include <hip/hip_runtime.h>
#include <hip/hip_bf16.h>
#include <stdint.h>

typedef __attribute__((ext_vector_type(4))) float f32x4;
typedef __attribute__((ext_vector_type(8))) short s16x8;
typedef __attribute__((ext_vector_type(4))) short s16x4;

#define B_   2
#define S_   2048
#define D_   1024
#define H_   16
#define HS_  64
#define TOK  (B_*S_)   // 4096
#define BH_  (B_*H_)   // 32

__device__ __forceinline__ short f2bf(float f){
  union { float f; uint32_t u; } v; v.f = f;
  uint32_t u = v.u;
  u += 0x7fffu + ((u >> 16) & 1u);   // round-to-nearest-even
  return (short)(u >> 16);
}

__device__ __forceinline__ void gload_lds16(const void* g, void* l){
  __builtin_amdgcn_global_load_lds((const __attribute__((address_space(1))) void*)g,
                                   (__attribute__((address_space(3))) void*)l, 16, 0, 0);
}

// ---------------- fp32 -> bf16 convert (vectorized) ----------------
__global__ void k_cvt(const float* __restrict__ src, short* __restrict__ dst, int n4){
  int i = blockIdx.x * blockDim.x + threadIdx.x;
  if (i < n4){
    float4 v = reinterpret_cast<const float4*>(src)[i];
    s16x4 o;
    o.x = f2bf(v.x); o.y = f2bf(v.y); o.z = f2bf(v.z); o.w = f2bf(v.w);
    reinterpret_cast<s16x4*>(dst)[i] = o;
  }
}

// ---------------- transpose + convert: src[K][N] f32 -> dst[N][K] bf16 ----------------
__global__ void k_tconv(const float* __restrict__ src, short* __restrict__ dst, int K, int N){
  __shared__ short tile[32][33];
  const int n0 = blockIdx.x * 32, k0 = blockIdx.y * 32;
  const int c = threadIdx.x & 31, r8 = threadIdx.x >> 5;
  #pragma unroll
  for (int j = 0; j < 4; j++){
    int k = r8 + j * 8;
    tile[c][k] = f2bf(src[(size_t)(k0 + k) * N + n0 + c]);
  }
  __syncthreads();
  #pragma unroll
  for (int j = 0; j < 4; j++){
    int nl = r8 + j * 8;
    dst[(size_t)(n0 + nl) * K + k0 + c] = tile[nl][c];
  }
}

// ---------------- bf16 GEMM, 128x128 tile, BK=32, K=1024 fixed ----------------
// A [M][1024] bf16 row-major, Bt [N][1024] bf16 (B transposed), bias fp32 [N].
// EPI 0: scatter to Q/K/V [bh][s][64] bf16 (+bias). EPI 1: fp32 out [M][1024] (+bias).
template<int EPI>
__global__ __launch_bounds__(256, 2) void k_gemm(
    const short* __restrict__ A, const short* __restrict__ Bt,
    const float* __restrict__ bias, void* __restrict__ outp)
{
  __shared__ short Al[128 * 32];
  __shared__ short Bl[128 * 32];
  const int tid = threadIdx.x;
  const int lane = tid & 63, wave = tid >> 6;
  const int m0 = blockIdx.x * 128, n0 = blockIdx.y * 128;
  const int wm = (wave >> 1) * 64, wn = (wave & 1) * 64;
  const int c = lane & 15, g = lane >> 4;

  f32x4 acc[4][4];
  #pragma unroll
  for (int i = 0; i < 4; i++)
    #pragma unroll
    for (int j = 0; j < 4; j++) acc[i][j] = (f32x4){0.f, 0.f, 0.f, 0.f};

  const short* Asrc = A + (size_t)m0 * 1024;
  const short* Bsrc = Bt + (size_t)n0 * 1024;

  for (int kt = 0; kt < 1024; kt += 32){
    __syncthreads();
    #pragma unroll
    for (int j = 0; j < 2; j++){
      int gc = (wave * 2 + j) * 64 + lane;   // 0..511 chunk id (16B chunks)
      int row = gc >> 2, c8 = gc & 3;
      gload_lds16(Asrc + (size_t)row * 1024 + kt + c8 * 8, Al + (size_t)(wave * 2 + j) * 512);
      gload_lds16(Bsrc + (size_t)row * 1024 + kt + c8 * 8, Bl + (size_t)(wave * 2 + j) * 512);
    }
    __syncthreads();   // compiler drains vmcnt(0) before s_barrier

    s16x8 af[4], bq[4];
    #pragma unroll
    for (int t = 0; t < 4; t++){
      af[t] = *(const s16x8*)&Al[(wm + t * 16 + c) * 32 + g * 8];
      bq[t] = *(const s16x8*)&Bl[(wn + t * 16 + c) * 32 + g * 8];
    }
    #pragma unroll
    for (int mt = 0; mt < 4; mt++)
      #pragma unroll
      for (int nt = 0; nt < 4; nt++)
        acc[mt][nt] = __builtin_amdgcn_mfma_f32_16x16x32_bf16(af[mt], bq[nt], acc[mt][nt], 0, 0, 0);
  }

  if (EPI == 0){
    short* Qb = (short*)outp;  // Q base; K at +QSZ, V at +2*QSZ
    const size_t QSZ = (size_t)BH_ * S_ * HS_;
    #pragma unroll
    for (int mt = 0; mt < 4; mt++){
      #pragma unroll
      for (int nt = 0; nt < 4; nt++){
        int n = n0 + wn + nt * 16 + c;
        float bv = bias[n];
        int sel = n >> 10, hn = (n >> 6) & 15, d = n & 63;
        #pragma unroll
        for (int r = 0; r < 4; r++){
          int token = m0 + wm + mt * 16 + g * 4 + r;
          int b = token >> 11, s = token & 2047;
          float v = acc[mt][nt][r] + bv;
          Qb[(size_t)sel * QSZ + ((size_t)(b * H_ + hn) * S_ + s) * HS_ + d] = f2bf(v);
        }
      }
    }
  } else {
    float* O = (float*)outp;
    #pragma unroll
    for (int mt = 0; mt < 4; mt++){
      #pragma unroll
      for (int nt = 0; nt < 4; nt++){
        int n = n0 + wn + nt * 16 + c;
        float bv = bias[n];
        #pragma unroll
        for (int r = 0; r < 4; r++){
          int token = m0 + wm + mt * 16 + g * 4 + r;
          O[(size_t)token * 1024 + n] = acc[mt][nt][r] + bv;
        }
      }
    }
  }
}

// ---------------- V [bh][s][64] -> Vt [bh][64][s] (bf16) ----------------
__global__ void k_vtrans(const short* __restrict__ Vg, short* __restrict__ Vt){
  __shared__ short t[64 * 80];
  const int bh = blockIdx.y;
  const int s0 = blockIdx.x * 64;
  const int tid = threadIdx.x;
  const int r = tid >> 3, c8 = (tid & 7) * 8;
  #pragma unroll
  for (int p = 0; p < 2; p++){
    int ss = r + p * 32;
    s16x8 v = *(const s16x8*)&Vg[((size_t)bh * S_ + s0 + ss) * HS_ + c8];
    #pragma unroll
    for (int i = 0; i < 8; i++) t[(c8 + i) * 80 + ss] = v[i];
  }
  __syncthreads();
  #pragma unroll
  for (int p = 0; p < 2; p++){
    int d = r + p * 32;
    s16x8 v = *(const s16x8*)&t[d * 80 + c8];
    *(s16x8*)&Vt[((size_t)bh * HS_ + d) * S_ + s0 + c8] = v;
  }
}

// ---------------- causal flash attention ----------------
// Q,K [bh][s][64] bf16; Vt [bh][64][s] bf16; Og [token][1024] bf16.
// Grid (32 qtiles, 32 bh), 4 waves; wave w owns q rows q0+16w..+15.
__global__ __launch_bounds__(256, 2) void k_attn(
    const short* __restrict__ Qg, const short* __restrict__ Kg,
    const short* __restrict__ Vt, short* __restrict__ Og)
{
  __shared__ short Kl[64 * 64];      // [kk][d]  XOR-swizzled
  __shared__ short Vl[64 * 64];      // [d][kk]  XOR-swizzled
  __shared__ short Pl[4][16 * 64];   // per-wave [q][kk] XOR-swizzled
  const int tid = threadIdx.x, lane = tid & 63, wave = tid >> 6;
  const int c = lane & 15, g = lane >> 4;
  const int qt = (int)gridDim.x - 1 - (int)blockIdx.x;   // long blocks first
  const int bh = blockIdx.y;
  const int q0 = qt * 64;
  const size_t basebh = (size_t)bh * S_ * HS_;

  // Q fragments held in registers for the whole block
  s16x8 qa0, qa1;
  {
    const short* qp = Qg + basebh + (size_t)(q0 + wave * 16 + c) * HS_ + g * 8;
    qa0 = *(const s16x8*)qp;          // d 0..31
    qa1 = *(const s16x8*)(qp + 32);   // d 32..63
  }
  f32x4 o_acc[4];
  #pragma unroll
  for (int i = 0; i < 4; i++) o_acc[i] = (f32x4){0.f, 0.f, 0.f, 0.f};
  float m_run[4], l_run[4];
  #pragma unroll
  for (int r = 0; r < 4; r++){ m_run[r] = -3e38f; l_run[r] = 0.f; }

  const int rr_ = tid >> 3, cc8 = (tid & 7) * 8;
  const short* Vtb = Vt + (size_t)bh * HS_ * S_;

  for (int kt = 0; kt <= qt; kt++){
    const int k0 = kt * 64;
    __syncthreads();
    // stage K tile [64][64] and Vt tile [64][64], swizzled writes
    #pragma unroll
    for (int p = 0; p < 2; p++){
      int row = rr_ + p * 32;
      s16x8 kv = *(const s16x8*)&Kg[basebh + (size_t)(k0 + row) * HS_ + cc8];
      *(s16x8*)&Kl[row * 64 + (cc8 ^ ((row & 7) * 8))] = kv;
      s16x8 vv = *(const s16x8*)&Vtb[(size_t)row * S_ + k0 + cc8];
      *(s16x8*)&Vl[row * 64 + (cc8 ^ ((row & 7) * 8))] = vv;
    }
    __syncthreads();

    // S = Q K^T  (16q x 64kk per wave)
    f32x4 s_acc[4];
    #pragma unroll
    for (int nt = 0; nt < 4; nt++){
      s_acc[nt] = (f32x4){0.f, 0.f, 0.f, 0.f};
      int row = nt * 16 + c;
      s16x8 b0 = *(const s16x8*)&Kl[row * 64 + ((g * 8) ^ ((row & 7) * 8))];
      s16x8 b1 = *(const s16x8*)&Kl[row * 64 + ((32 + g * 8) ^ ((row & 7) * 8))];
      s_acc[nt] = __builtin_amdgcn_mfma_f32_16x16x32_bf16(qa0, b0, s_acc[nt], 0, 0, 0);
      s_acc[nt] = __builtin_amdgcn_mfma_f32_16x16x32_bf16(qa1, b1, s_acc[nt], 0, 0, 0);
    }

    // scale + causal mask
    float sc[4][4];
    const bool diag = (kt == qt);
    #pragma unroll
    for (int nt = 0; nt < 4; nt++)
      #pragma unroll
      for (int r = 0; r < 4; r++){
        float v = s_acc[nt][r] * 0.125f;
        if (diag){
          int kkg = k0 + nt * 16 + c;
          int qg2 = q0 + wave * 16 + g * 4 + r;
          if (kkg > qg2) v = -3e38f;
        }
        sc[nt][r] = v;
      }

    // online softmax (row lives on 16 consecutive lanes; shfl_xor 1,2,4,8)
    float fexp[4];
    #pragma unroll
    for (int r = 0; r < 4; r++){
      float mx = fmaxf(fmaxf(sc[0][r], sc[1][r]), fmaxf(sc[2][r], sc[3][r]));
      #pragma unroll
      for (int off = 1; off < 16; off <<= 1) mx = fmaxf(mx, __shfl_xor(mx, off));
      float mnew = fmaxf(m_run[r], mx);
      fexp[r] = __expf(m_run[r] - mnew);
      m_run[r] = mnew;
    }
    float rs[4] = {0.f, 0.f, 0.f, 0.f};
    short pb[4][4];
    #pragma unroll
    for (int nt = 0; nt < 4; nt++)
      #pragma unroll
      for (int r = 0; r < 4; r++){
        float p = __expf(sc[nt][r] - m_run[r]);
        rs[r] += p;
        pb[nt][r] = f2bf(p);
      }
    #pragma unroll
    for (int r = 0; r < 4; r++){
      float s = rs[r];
      #pragma unroll
      for (int off = 1; off < 16; off <<= 1) s += __shfl_xor(s, off);
      l_run[r] = l_run[r] * fexp[r] + s;
    }
    #pragma unroll
    for (int nt = 0; nt < 4; nt++){
      f32x4 t = o_acc[nt];
      t[0] *= fexp[0]; t[1] *= fexp[1]; t[2] *= fexp[2]; t[3] *= fexp[3];
      o_acc[nt] = t;
    }

    // P -> per-wave LDS (bf16, swizzled)
    short* Pw = &Pl[wave][0];
    #pragma unroll
    for (int nt = 0; nt < 4; nt++)
      #pragma unroll
      for (int r = 0; r < 4; r++){
        int row = g * 4 + r;
        int e = nt * 16 + c;
        Pw[row * 64 + (e ^ ((row & 7) * 8))] = pb[nt][r];
      }
    __syncthreads();   // lgkm drain + keep waves in lockstep

    // O += P V
    #pragma unroll
    for (int nt = 0; nt < 4; nt++){
      int row = nt * 16 + c;   // Vl row = d
      #pragma unroll
      for (int ks = 0; ks < 2; ks++){
        s16x8 pa = *(const s16x8*)&Pw[c * 64 + ((ks * 32 + g * 8) ^ ((c & 7) * 8))];
        s16x8 vb = *(const s16x8*)&Vl[row * 64 + ((ks * 32 + g * 8) ^ ((row & 7) * 8))];
        o_acc[nt] = __builtin_amdgcn_mfma_f32_16x16x32_bf16(pa, vb, o_acc[nt], 0, 0, 0);
      }
    }
  }

  // epilogue: O / l -> [token][1024] bf16
  const int h = bh & 15, b = bh >> 4;
  float inv[4];
  #pragma unroll
  for (int r = 0; r < 4; r++) inv[r] = 1.0f / l_run[r];
  #pragma unroll
  for (int nt = 0; nt < 4; nt++)
    #pragma unroll
    for (int r = 0; r < 4; r++){
      int q = q0 + wave * 16 + g * 4 + r;
      int token = b * S_ + q;
      Og[(size_t)token * D_ + h * HS_ + nt * 16 + c] = f2bf(o_acc[nt][r] * inv[r]);
    }
}

extern "C" void kernel_launch(void* const* d_in, const int* in_sizes, int n_in,
                              void* d_out, int out_size, void* d_ws, size_t ws_size,
                              hipStream_t stream)
{
  const float* x    = (const float*)d_in[0];
  const float* Wqkv = (const float*)d_in[1];
  const float* bqkv = (const float*)d_in[2];
  const float* Wout = (const float*)d_in[3];
  const float* bout = (const float*)d_in[4];

  char* ws = (char*)d_ws;
  short* xb     = (short*)(ws);                 //  8 MB [4096][1024] bf16 (reused as O_tok)
  short* Wqkv_t = (short*)(ws + 8388608);       //  6 MB [3072][1024]
  short* Wout_t = (short*)(ws + 14680064);      //  2 MB [1024][1024]
  short* Qg     = (short*)(ws + 16777216);      //  8 MB [32][2048][64]
  short* Kg     = Qg + 4194304;                 //  8 MB
  short* Vg     = Qg + 8388608;                 //  8 MB
  short* Vt     = (short*)(ws + 41943040);      //  8 MB [32][64][2048]
  short* Otok   = xb;                           //  reuse (xb dead after QKV GEMM)

  k_cvt<<<4096, 256, 0, stream>>>(x, xb, TOK * D_ / 4);
  k_tconv<<<dim3(96, 32), 256, 0, stream>>>(Wqkv, Wqkv_t, 1024, 3072);
  k_tconv<<<dim3(32, 32), 256, 0, stream>>>(Wout, Wout_t, 1024, 1024);
  k_gemm<0><<<dim3(32, 24), 256, 0, stream>>>(xb, Wqkv_t, bqkv, (void*)Qg);
  k_vtrans<<<dim3(32, 32), 256, 0, stream>>>(Vg, Vt);
  k_attn<<<dim3(32, 32), 256, 0, stream>>>(Qg, Kg, Vt, Otok);
  k_gemm<1><<<dim3(32, 8), 256, 0, stream>>>(Otok, Wout_t, bout, d_out);
}

// Round 2
// 289.997 us; speedup vs baseline: 1.0742x; 1.0742x over previous
//
#include <hip/hip_runtime.h>
#include <hip/hip_bf16.h>
#include <stdint.h>

typedef __attribute__((ext_vector_type(4))) float f32x4;
typedef __attribute__((ext_vector_type(8))) short s16x8;
typedef __attribute__((ext_vector_type(4))) short s16x4;

#define B_   2
#define S_   2048
#define D_   1024
#define H_   16
#define HS_  64
#define TOK  (B_*S_)   // 4096
#define BH_  (B_*H_)   // 32

__device__ __forceinline__ short f2bf(float f){
  union { float f; uint32_t u; } v; v.f = f;
  uint32_t u = v.u;
  u += 0x7fffu + ((u >> 16) & 1u);   // round-to-nearest-even
  return (short)(u >> 16);
}

__device__ __forceinline__ void gload_lds16(const void* g, void* l){
  __builtin_amdgcn_global_load_lds((const __attribute__((address_space(1))) void*)g,
                                   (__attribute__((address_space(3))) void*)l, 16, 0, 0);
}

// ---------------- fp32 -> bf16 convert (vectorized) ----------------
__global__ void k_cvt(const float* __restrict__ src, short* __restrict__ dst, int n4){
  int i = blockIdx.x * blockDim.x + threadIdx.x;
  if (i < n4){
    float4 v = reinterpret_cast<const float4*>(src)[i];
    s16x4 o;
    o.x = f2bf(v.x); o.y = f2bf(v.y); o.z = f2bf(v.z); o.w = f2bf(v.w);
    reinterpret_cast<s16x4*>(dst)[i] = o;
  }
}

// ---------------- transpose + convert: src[K][N] f32 -> dst[N][K] bf16 ----------------
__global__ void k_tconv(const float* __restrict__ src, short* __restrict__ dst, int K, int N){
  __shared__ short tile[32][33];
  const int n0 = blockIdx.x * 32, k0 = blockIdx.y * 32;
  const int c = threadIdx.x & 31, r8 = threadIdx.x >> 5;
  #pragma unroll
  for (int j = 0; j < 4; j++){
    int k = r8 + j * 8;
    tile[c][k] = f2bf(src[(size_t)(k0 + k) * N + n0 + c]);
  }
  __syncthreads();
  #pragma unroll
  for (int j = 0; j < 4; j++){
    int nl = r8 + j * 8;
    dst[(size_t)(n0 + nl) * K + k0 + c] = tile[nl][c];
  }
}

// ---------------- bf16 GEMM, 128x128 tile, BK=32, K=1024 fixed ----------------
// A [M][1024] bf16 row-major, Bt [N][1024] bf16 (B transposed), bias fp32 [N].
// EPI 0: scatter to Q/K/V [bh][s][64] bf16 (+bias). EPI 1: fp32 out [M][1024] (+bias).
template<int EPI>
__global__ __launch_bounds__(256, 2) void k_gemm(
    const short* __restrict__ A, const short* __restrict__ Bt,
    const float* __restrict__ bias, void* __restrict__ outp)
{
  __shared__ short Al[128 * 32];
  __shared__ short Bl[128 * 32];
  const int tid = threadIdx.x;
  const int lane = tid & 63, wave = tid >> 6;
  const int m0 = blockIdx.x * 128, n0 = blockIdx.y * 128;
  const int wm = (wave >> 1) * 64, wn = (wave & 1) * 64;
  const int c = lane & 15, g = lane >> 4;

  f32x4 acc[4][4];
  #pragma unroll
  for (int i = 0; i < 4; i++)
    #pragma unroll
    for (int j = 0; j < 4; j++) acc[i][j] = (f32x4){0.f, 0.f, 0.f, 0.f};

  const short* Asrc = A + (size_t)m0 * 1024;
  const short* Bsrc = Bt + (size_t)n0 * 1024;

  for (int kt = 0; kt < 1024; kt += 32){
    __syncthreads();
    #pragma unroll
    for (int j = 0; j < 2; j++){
      int gc = (wave * 2 + j) * 64 + lane;   // 0..511 chunk id (16B chunks)
      int row = gc >> 2, c8 = gc & 3;
      gload_lds16(Asrc + (size_t)row * 1024 + kt + c8 * 8, Al + (size_t)(wave * 2 + j) * 512);
      gload_lds16(Bsrc + (size_t)row * 1024 + kt + c8 * 8, Bl + (size_t)(wave * 2 + j) * 512);
    }
    __syncthreads();   // compiler drains vmcnt(0) before s_barrier

    s16x8 af[4], bq[4];
    #pragma unroll
    for (int t = 0; t < 4; t++){
      af[t] = *(const s16x8*)&Al[(wm + t * 16 + c) * 32 + g * 8];
      bq[t] = *(const s16x8*)&Bl[(wn + t * 16 + c) * 32 + g * 8];
    }
    #pragma unroll
    for (int mt = 0; mt < 4; mt++)
      #pragma unroll
      for (int nt = 0; nt < 4; nt++)
        acc[mt][nt] = __builtin_amdgcn_mfma_f32_16x16x32_bf16(af[mt], bq[nt], acc[mt][nt], 0, 0, 0);
  }

  if (EPI == 0){
    short* Qb = (short*)outp;  // Q base; K at +QSZ, V at +2*QSZ
    const size_t QSZ = (size_t)BH_ * S_ * HS_;
    #pragma unroll
    for (int mt = 0; mt < 4; mt++){
      #pragma unroll
      for (int nt = 0; nt < 4; nt++){
        int n = n0 + wn + nt * 16 + c;
        float bv = bias[n];
        int sel = n >> 10, hn = (n >> 6) & 15, d = n & 63;
        #pragma unroll
        for (int r = 0; r < 4; r++){
          int token = m0 + wm + mt * 16 + g * 4 + r;
          int b = token >> 11, s = token & 2047;
          float v = acc[mt][nt][r] + bv;
          Qb[(size_t)sel * QSZ + ((size_t)(b * H_ + hn) * S_ + s) * HS_ + d] = f2bf(v);
        }
      }
    }
  } else {
    float* O = (float*)outp;
    #pragma unroll
    for (int mt = 0; mt < 4; mt++){
      #pragma unroll
      for (int nt = 0; nt < 4; nt++){
        int n = n0 + wn + nt * 16 + c;
        float bv = bias[n];
        #pragma unroll
        for (int r = 0; r < 4; r++){
          int token = m0 + wm + mt * 16 + g * 4 + r;
          O[(size_t)token * 1024 + n] = acc[mt][nt][r] + bv;
        }
      }
    }
  }
}

// ---------------- V [bh][s][64] -> Vt [bh][64][s] (bf16) ----------------
__global__ void k_vtrans(const short* __restrict__ Vg, short* __restrict__ Vt){
  __shared__ short t[64 * 80];
  const int bh = blockIdx.y;
  const int s0 = blockIdx.x * 64;
  const int tid = threadIdx.x;
  const int r = tid >> 3, c8 = (tid & 7) * 8;
  #pragma unroll
  for (int p = 0; p < 2; p++){
    int ss = r + p * 32;
    s16x8 v = *(const s16x8*)&Vg[((size_t)bh * S_ + s0 + ss) * HS_ + c8];
    #pragma unroll
    for (int i = 0; i < 8; i++) t[(c8 + i) * 80 + ss] = v[i];
  }
  __syncthreads();
  #pragma unroll
  for (int p = 0; p < 2; p++){
    int d = r + p * 32;
    s16x8 v = *(const s16x8*)&t[d * 80 + c8];
    *(s16x8*)&Vt[((size_t)bh * HS_ + d) * S_ + s0 + c8] = v;
  }
}

// ---------------- causal flash attention: wave-independent, no barriers ----------------
// Q,K [bh][s][64] bf16; Vt [bh][64][s] bf16; Og [token][1024] bf16.
// Each wave owns 16 q-rows; K/Vt read straight from global (L2-resident, 512KB/bh).
// Swapped QK^T (S^T = mfma(K, Q)) so each lane holds 16 scores of ONE q-row:
// softmax = in-lane reduce + 2 shfl_xor. P goes through a per-wave swizzled LDS
// buffer (4x ds_write_b64 -> 2x ds_read_b128), no __syncthreads anywhere.
__global__ __launch_bounds__(256, 4) void k_attn(
    const short* __restrict__ Qg, const short* __restrict__ Kg,
    const short* __restrict__ Vt, short* __restrict__ Og)
{
  __shared__ short Pl[4][16 * 64];   // per-wave P rows [q=c][kk], XOR-swizzled
  const int tid = threadIdx.x, lane = tid & 63, wave = tid >> 6;
  const int c = lane & 15, g = lane >> 4;
  // block -> (bh, qg): XCD-chunked by bh, long q-groups first (LPT)
  const int p = blockIdx.x;
  const int xcd = p & 7, j = p >> 3;
  const int bh = xcd * 4 + (j & 3);
  const int qg = 31 - ((j >> 2) & 31);
  const int qt16 = qg * 4 + wave;    // all 4 waves: identical k-iter count
  const int q0 = qt16 * 16;
  const size_t basebh = (size_t)bh * S_ * HS_;
  const short* Kb  = Kg + basebh;
  const short* Vtb = Vt + (size_t)bh * HS_ * S_;

  // Q as MFMA B-fragments (lane holds Q[q0+c][g*8..+7] per 32-d chunk)
  s16x8 qb0, qb1;
  {
    const short* qp = Qg + basebh + (size_t)(q0 + c) * HS_ + g * 8;
    qb0 = *(const s16x8*)qp;
    qb1 = *(const s16x8*)(qp + 32);
  }
  f32x4 o_acc[4];
  #pragma unroll
  for (int i = 0; i < 4; i++) o_acc[i] = (f32x4){0.f, 0.f, 0.f, 0.f};
  float m_c = -3e38f, l_c = 0.f;    // softmax state for q-row (q0 + c)
  short* Pw = &Pl[wave][0];
  const int swr = (c & 7) * 8;      // swizzle (short units)
  const int nkt = qg + 1;
  const float SC = 0.125f * 1.44269504f;  // scale * log2(e); use exp2

  for (int kt = 0; kt < nkt; kt++){
    const int k0 = kt * 64;
    const bool diag = (kt == nkt - 1);

    // S^T = K * Q^T : st[nt][r] = S[q0+c][k0 + nt*16 + g*4 + r]
    f32x4 st[4];
    #pragma unroll
    for (int nt = 0; nt < 4; nt++){
      const short* kp = Kb + (size_t)(k0 + nt * 16 + c) * HS_ + g * 8;
      s16x8 ka0 = *(const s16x8*)kp;
      s16x8 ka1 = *(const s16x8*)(kp + 32);
      f32x4 a = (f32x4){0.f, 0.f, 0.f, 0.f};
      a = __builtin_amdgcn_mfma_f32_16x16x32_bf16(ka0, qb0, a, 0, 0, 0);
      a = __builtin_amdgcn_mfma_f32_16x16x32_bf16(ka1, qb1, a, 0, 0, 0);
      st[nt] = a;
    }

    // scale + causal mask + in-lane max
    float sc[16];
    float tmax = -3e38f;
    #pragma unroll
    for (int nt = 0; nt < 4; nt++)
      #pragma unroll
      for (int r = 0; r < 4; r++){
        float v = st[nt][r] * SC;
        if (diag && (k0 + nt * 16 + g * 4 + r > q0 + c)) v = -3e38f;
        sc[nt * 4 + r] = v;
        tmax = fmaxf(tmax, v);
      }
    // row q0+c lives on lanes {c, c+16, c+32, c+48}
    tmax = fmaxf(tmax, __shfl_xor(tmax, 16));
    tmax = fmaxf(tmax, __shfl_xor(tmax, 32));
    float mnew = fmaxf(m_c, tmax);
    float fe = exp2f(m_c - mnew);
    m_c = mnew;

    float rs = 0.f;
    short pb[16];
    #pragma unroll
    for (int i = 0; i < 16; i++){
      float pv = exp2f(sc[i] - m_c);
      rs += pv;
      pb[i] = f2bf(pv);
    }
    rs += __shfl_xor(rs, 16);
    rs += __shfl_xor(rs, 32);
    l_c = l_c * fe + rs;

    // P[q=c][kk] -> per-wave LDS (vectorized b64, swizzled)
    #pragma unroll
    for (int nt = 0; nt < 4; nt++){
      s16x4 pk = (s16x4){pb[nt*4+0], pb[nt*4+1], pb[nt*4+2], pb[nt*4+3]};
      *(s16x4*)&Pw[c * 64 + ((nt * 16 + g * 4) ^ swr)] = pk;
    }

    // broadcast fexp to o_acc's row layout (row q = g*4+r) and rescale
    float feq[4];
    #pragma unroll
    for (int r = 0; r < 4; r++) feq[r] = __shfl(fe, g * 4 + r);
    #pragma unroll
    for (int nt = 0; nt < 4; nt++){
      f32x4 t = o_acc[nt];
      t[0] *= feq[0]; t[1] *= feq[1]; t[2] *= feq[2]; t[3] *= feq[3];
      o_acc[nt] = t;
    }

    // O += P V  (pa from per-wave LDS; V fragments straight from Vt/L2)
    #pragma unroll
    for (int ks = 0; ks < 2; ks++){
      s16x8 pa = *(const s16x8*)&Pw[c * 64 + ((ks * 32 + g * 8) ^ swr)];
      #pragma unroll
      for (int nt = 0; nt < 4; nt++){
        s16x8 vb = *(const s16x8*)(Vtb + (size_t)(nt * 16 + c) * S_ + k0 + ks * 32 + g * 8);
        o_acc[nt] = __builtin_amdgcn_mfma_f32_16x16x32_bf16(pa, vb, o_acc[nt], 0, 0, 0);
      }
    }
  }

  // epilogue: O / l -> [token][1024] bf16  (o_acc[nt][r] = O[q=g*4+r][d=nt*16+c])
  float linv = 1.0f / l_c;
  float lr[4];
  #pragma unroll
  for (int r = 0; r < 4; r++) lr[r] = __shfl(linv, g * 4 + r);
  const int h = bh & 15, b = bh >> 4;
  #pragma unroll
  for (int nt = 0; nt < 4; nt++)
    #pragma unroll
    for (int r = 0; r < 4; r++){
      int q = q0 + g * 4 + r;
      Og[(size_t)(b * S_ + q) * D_ + h * HS_ + nt * 16 + c] = f2bf(o_acc[nt][r] * lr[r]);
    }
}

extern "C" void kernel_launch(void* const* d_in, const int* in_sizes, int n_in,
                              void* d_out, int out_size, void* d_ws, size_t ws_size,
                              hipStream_t stream)
{
  const float* x    = (const float*)d_in[0];
  const float* Wqkv = (const float*)d_in[1];
  const float* bqkv = (const float*)d_in[2];
  const float* Wout = (const float*)d_in[3];
  const float* bout = (const float*)d_in[4];

  char* ws = (char*)d_ws;
  short* xb     = (short*)(ws);                 //  8 MB [4096][1024] bf16 (reused as O_tok)
  short* Wqkv_t = (short*)(ws + 8388608);       //  6 MB [3072][1024]
  short* Wout_t = (short*)(ws + 14680064);      //  2 MB [1024][1024]
  short* Qg     = (short*)(ws + 16777216);      //  8 MB [32][2048][64]
  short* Kg     = Qg + 4194304;                 //  8 MB
  short* Vg     = Qg + 8388608;                 //  8 MB
  short* Vt     = (short*)(ws + 41943040);      //  8 MB [32][64][2048]
  short* Otok   = xb;                           //  reuse (xb dead after QKV GEMM)

  k_cvt<<<4096, 256, 0, stream>>>(x, xb, TOK * D_ / 4);
  k_tconv<<<dim3(96, 32), 256, 0, stream>>>(Wqkv, Wqkv_t, 1024, 3072);
  k_tconv<<<dim3(32, 32), 256, 0, stream>>>(Wout, Wout_t, 1024, 1024);
  k_gemm<0><<<dim3(32, 24), 256, 0, stream>>>(xb, Wqkv_t, bqkv, (void*)Qg);
  k_vtrans<<<dim3(32, 32), 256, 0, stream>>>(Vg, Vt);
  k_attn<<<dim3(1024), 256, 0, stream>>>(Qg, Kg, Vt, Otok);
  k_gemm<1><<<dim3(32, 8), 256, 0, stream>>>(Otok, Wout_t, bout, d_out);
}

// Round 4
// 267.523 us; speedup vs baseline: 1.1645x; 1.0840x over previous
//
#include <hip/hip_runtime.h>
#include <hip/hip_bf16.h>
#include <stdint.h>

typedef __attribute__((ext_vector_type(4))) float f32x4;
typedef __attribute__((ext_vector_type(8))) short s16x8;
typedef __attribute__((ext_vector_type(4))) short s16x4;

#define B_   2
#define S_   2048
#define D_   1024
#define H_   16
#define HS_  64
#define TOK  (B_*S_)   // 4096
#define BH_  (B_*H_)   // 32

__device__ __forceinline__ short f2bf(float f){
  union { float f; uint32_t u; } v; v.f = f;
  uint32_t u = v.u;
  u += 0x7fffu + ((u >> 16) & 1u);   // round-to-nearest-even
  return (short)(u >> 16);
}

__device__ __forceinline__ uint32_t cvt_pk_bf16(float lo, float hi){
  uint32_t r;
  asm("v_cvt_pk_bf16_f32 %0, %1, %2" : "=v"(r) : "v"(lo), "v"(hi));
  return r;
}

__device__ __forceinline__ void gload_lds16(const void* g, void* l){
  __builtin_amdgcn_global_load_lds((const __attribute__((address_space(1))) void*)g,
                                   (__attribute__((address_space(3))) void*)l, 16, 0, 0);
}

// ---------------- fp32 -> bf16 convert (vectorized) ----------------
__global__ void k_cvt(const float* __restrict__ src, short* __restrict__ dst, int n4){
  int i = blockIdx.x * blockDim.x + threadIdx.x;
  if (i < n4){
    float4 v = reinterpret_cast<const float4*>(src)[i];
    s16x4 o;
    o.x = f2bf(v.x); o.y = f2bf(v.y); o.z = f2bf(v.z); o.w = f2bf(v.w);
    reinterpret_cast<s16x4*>(dst)[i] = o;
  }
}

// ---------------- transpose + convert: src[K][N] f32 -> dst[N][K] bf16 ----------------
__global__ void k_tconv(const float* __restrict__ src, short* __restrict__ dst, int K, int N){
  __shared__ short tile[32][33];
  const int n0 = blockIdx.x * 32, k0 = blockIdx.y * 32;
  const int c = threadIdx.x & 31, r8 = threadIdx.x >> 5;
  #pragma unroll
  for (int j = 0; j < 4; j++){
    int k = r8 + j * 8;
    tile[c][k] = f2bf(src[(size_t)(k0 + k) * N + n0 + c]);
  }
  __syncthreads();
  #pragma unroll
  for (int j = 0; j < 4; j++){
    int nl = r8 + j * 8;
    dst[(size_t)(n0 + nl) * K + k0 + c] = tile[nl][c];
  }
}

// ---------------- bf16 GEMM, 128x128 tile, BK=32, K=1024 fixed ----------------
template<int EPI>
__global__ __launch_bounds__(256, 2) void k_gemm(
    const short* __restrict__ A, const short* __restrict__ Bt,
    const float* __restrict__ bias, void* __restrict__ outp)
{
  __shared__ short Al[128 * 32];
  __shared__ short Bl[128 * 32];
  const int tid = threadIdx.x;
  const int lane = tid & 63, wave = tid >> 6;
  const int m0 = blockIdx.x * 128, n0 = blockIdx.y * 128;
  const int wm = (wave >> 1) * 64, wn = (wave & 1) * 64;
  const int c = lane & 15, g = lane >> 4;

  f32x4 acc[4][4];
  #pragma unroll
  for (int i = 0; i < 4; i++)
    #pragma unroll
    for (int j = 0; j < 4; j++) acc[i][j] = (f32x4){0.f, 0.f, 0.f, 0.f};

  const short* Asrc = A + (size_t)m0 * 1024;
  const short* Bsrc = Bt + (size_t)n0 * 1024;

  for (int kt = 0; kt < 1024; kt += 32){
    __syncthreads();
    #pragma unroll
    for (int j = 0; j < 2; j++){
      int gc = (wave * 2 + j) * 64 + lane;
      int row = gc >> 2, c8 = gc & 3;
      gload_lds16(Asrc + (size_t)row * 1024 + kt + c8 * 8, Al + (size_t)(wave * 2 + j) * 512);
      gload_lds16(Bsrc + (size_t)row * 1024 + kt + c8 * 8, Bl + (size_t)(wave * 2 + j) * 512);
    }
    __syncthreads();

    s16x8 af[4], bq[4];
    #pragma unroll
    for (int t = 0; t < 4; t++){
      af[t] = *(const s16x8*)&Al[(wm + t * 16 + c) * 32 + g * 8];
      bq[t] = *(const s16x8*)&Bl[(wn + t * 16 + c) * 32 + g * 8];
    }
    #pragma unroll
    for (int mt = 0; mt < 4; mt++)
      #pragma unroll
      for (int nt = 0; nt < 4; nt++)
        acc[mt][nt] = __builtin_amdgcn_mfma_f32_16x16x32_bf16(af[mt], bq[nt], acc[mt][nt], 0, 0, 0);
  }

  if (EPI == 0){
    short* Qb = (short*)outp;
    const size_t QSZ = (size_t)BH_ * S_ * HS_;
    #pragma unroll
    for (int mt = 0; mt < 4; mt++){
      #pragma unroll
      for (int nt = 0; nt < 4; nt++){
        int n = n0 + wn + nt * 16 + c;
        float bv = bias[n];
        int sel = n >> 10, hn = (n >> 6) & 15, d = n & 63;
        #pragma unroll
        for (int r = 0; r < 4; r++){
          int token = m0 + wm + mt * 16 + g * 4 + r;
          int b = token >> 11, s = token & 2047;
          float v = acc[mt][nt][r] + bv;
          Qb[(size_t)sel * QSZ + ((size_t)(b * H_ + hn) * S_ + s) * HS_ + d] = f2bf(v);
        }
      }
    }
  } else {
    float* O = (float*)outp;
    #pragma unroll
    for (int mt = 0; mt < 4; mt++){
      #pragma unroll
      for (int nt = 0; nt < 4; nt++){
        int n = n0 + wn + nt * 16 + c;
        float bv = bias[n];
        #pragma unroll
        for (int r = 0; r < 4; r++){
          int token = m0 + wm + mt * 16 + g * 4 + r;
          O[(size_t)token * 1024 + n] = acc[mt][nt][r] + bv;
        }
      }
    }
  }
}

// ---------------- V [bh][s][64] -> Vt [bh][64][s] (bf16) ----------------
__global__ void k_vtrans(const short* __restrict__ Vg, short* __restrict__ Vt){
  __shared__ short t[64 * 80];
  const int bh = blockIdx.y;
  const int s0 = blockIdx.x * 64;
  const int tid = threadIdx.x;
  const int r = tid >> 3, c8 = (tid & 7) * 8;
  #pragma unroll
  for (int p = 0; p < 2; p++){
    int ss = r + p * 32;
    s16x8 v = *(const s16x8*)&Vg[((size_t)bh * S_ + s0 + ss) * HS_ + c8];
    #pragma unroll
    for (int i = 0; i < 8; i++) t[(c8 + i) * 80 + ss] = v[i];
  }
  __syncthreads();
  #pragma unroll
  for (int p = 0; p < 2; p++){
    int d = r + p * 32;
    s16x8 v = *(const s16x8*)&t[d * 80 + c8];
    *(s16x8*)&Vt[((size_t)bh * HS_ + d) * S_ + s0 + c8] = v;
  }
}

// ---------------- causal flash attention: 4-way split-K per q-tile ----------------
// Block (256 thr) owns one 16-row q-tile; wave w handles k-tiles kt ≡ w (mod 4),
// partials (m,l,O) merged via LDS at the end. K/Vt fragments loaded straight from
// global (L2-resident); all 16 loads issued upfront per tile for latency overlap.
__global__ __launch_bounds__(256, 4) void k_attn(
    const short* __restrict__ Qg, const short* __restrict__ Kg,
    const short* __restrict__ Vt, short* __restrict__ Og)
{
  __shared__ short Pl[4][16 * 64];   // per-wave P rows [q=c][kk], XOR-swizzled
  __shared__ float Mo[3][64][18];    // partial O from waves 1..3 (stride 72B: 8B-aligned)
  __shared__ float Ml[3][16];        // partial m
  __shared__ float Ll[3][16];        // partial l
  __shared__ float Fq[4][16];        // merge factors per row
  __shared__ float Linv[16];

  const int tid = threadIdx.x, lane = tid & 63, wave = tid >> 6;
  const int c = lane & 15, g = lane >> 4;
  // block -> (bh, qt16): XCD-chunked by bh, longest q-tiles dispatched first
  const int p = blockIdx.x;
  const int xcd = p & 7, j = p >> 3;
  const int bh = xcd * 4 + (j & 3);
  const int qt16 = 127 - (j >> 2);         // 0..127, descending
  const int q0 = qt16 * 16;
  const int nkt = (qt16 >> 2) + 1;         // # of 64-key tiles
  const size_t basebh = (size_t)bh * S_ * HS_;
  const short* Kb  = Kg + basebh;
  const short* Vtb = Vt + (size_t)bh * HS_ * S_;

  // Q as MFMA B-fragments (lane holds Q[q0+c][g*8..+7] per 32-d chunk)
  s16x8 qb0, qb1;
  {
    const short* qp = Qg + basebh + (size_t)(q0 + c) * HS_ + g * 8;
    qb0 = *(const s16x8*)qp;
    qb1 = *(const s16x8*)(qp + 32);
  }
  f32x4 o_acc[4];
  #pragma unroll
  for (int i = 0; i < 4; i++) o_acc[i] = (f32x4){0.f, 0.f, 0.f, 0.f};
  float m_c = -3e38f, l_c = 0.f;
  short* Pw = &Pl[wave][0];
  const int swr = (c & 7) * 8;
  const float SC = 0.125f * 1.44269504f;   // scale * log2(e)

  for (int kt = wave; kt < nkt; kt += 4){
    const int k0 = kt * 64;
    const bool diag = (kt == nkt - 1);

    // ---- all 16 fragment loads issued upfront (64 VGPR in flight) ----
    s16x8 ka[8], va[8];
    #pragma unroll
    for (int nt = 0; nt < 4; nt++){
      const short* kp = Kb + (size_t)(k0 + nt * 16 + c) * HS_ + g * 8;
      ka[nt * 2]     = *(const s16x8*)kp;
      ka[nt * 2 + 1] = *(const s16x8*)(kp + 32);
      const short* vp = Vtb + (size_t)(nt * 16 + c) * S_ + k0 + g * 8;
      va[nt * 2]     = *(const s16x8*)vp;
      va[nt * 2 + 1] = *(const s16x8*)(vp + 32);
    }

    // ---- S^T = K * Q^T : st[nt][r] = S[q0+c][k0 + nt*16 + g*4 + r] ----
    f32x4 st[4];
    #pragma unroll
    for (int nt = 0; nt < 4; nt++){
      f32x4 a = (f32x4){0.f, 0.f, 0.f, 0.f};
      a = __builtin_amdgcn_mfma_f32_16x16x32_bf16(ka[nt * 2],     qb0, a, 0, 0, 0);
      a = __builtin_amdgcn_mfma_f32_16x16x32_bf16(ka[nt * 2 + 1], qb1, a, 0, 0, 0);
      st[nt] = a;
    }

    // ---- scale + causal mask + in-lane max ----
    float sc[16];
    float tmax = -3e38f;
    #pragma unroll
    for (int nt = 0; nt < 4; nt++)
      #pragma unroll
      for (int r = 0; r < 4; r++){
        float v = st[nt][r] * SC;
        if (diag && (k0 + nt * 16 + g * 4 + r > q0 + c)) v = -3e38f;
        sc[nt * 4 + r] = v;
        tmax = fmaxf(tmax, v);
      }
    tmax = fmaxf(tmax, __shfl_xor(tmax, 16));
    tmax = fmaxf(tmax, __shfl_xor(tmax, 32));

    // T13: skip rescale when running max doesn't grow (wave-uniform)
    if (!__all(tmax <= m_c)){
      float mnew = fmaxf(m_c, tmax);
      float fe = exp2f(m_c - mnew);
      m_c = mnew;
      l_c *= fe;
      float feq[4];
      #pragma unroll
      for (int r = 0; r < 4; r++) feq[r] = __shfl(fe, g * 4 + r);
      #pragma unroll
      for (int nt = 0; nt < 4; nt++){
        f32x4 t = o_acc[nt];
        t[0] *= feq[0]; t[1] *= feq[1]; t[2] *= feq[2]; t[3] *= feq[3];
        o_acc[nt] = t;
      }
    }

    float rs = 0.f;
    float pv[16];
    #pragma unroll
    for (int i = 0; i < 16; i++){
      pv[i] = exp2f(sc[i] - m_c);
      rs += pv[i];
    }
    rs += __shfl_xor(rs, 16);
    rs += __shfl_xor(rs, 32);
    l_c += rs;

    // ---- P[q=c][kk] -> per-wave LDS via hw cvt_pk (vectorized b64, swizzled) ----
    #pragma unroll
    for (int nt = 0; nt < 4; nt++){
      uint2 pk;
      pk.x = cvt_pk_bf16(pv[nt * 4 + 0], pv[nt * 4 + 1]);
      pk.y = cvt_pk_bf16(pv[nt * 4 + 2], pv[nt * 4 + 3]);
      *(uint2*)&Pw[c * 64 + ((nt * 16 + g * 4) ^ swr)] = pk;
    }

    // ---- O += P V ----
    #pragma unroll
    for (int ks = 0; ks < 2; ks++){
      s16x8 pa = *(const s16x8*)&Pw[c * 64 + ((ks * 32 + g * 8) ^ swr)];
      #pragma unroll
      for (int nt = 0; nt < 4; nt++)
        o_acc[nt] = __builtin_amdgcn_mfma_f32_16x16x32_bf16(pa, va[nt * 2 + ks], o_acc[nt], 0, 0, 0);
    }
  }

  // ---- split-K merge ----
  if (wave > 0){
    int w = wave - 1;
    #pragma unroll
    for (int nt = 0; nt < 4; nt++){
      *(float2*)&Mo[w][lane][nt * 4]     = (float2){o_acc[nt][0], o_acc[nt][1]};
      *(float2*)&Mo[w][lane][nt * 4 + 2] = (float2){o_acc[nt][2], o_acc[nt][3]};
    }
    if (lane < 16){ Ml[w][c] = m_c; Ll[w][c] = l_c; }
  }
  __syncthreads();
  if (wave == 0){
    if (lane < 16){
      float mw0 = Ml[0][c], mw1 = Ml[1][c], mw2 = Ml[2][c];
      float m_tot = fmaxf(fmaxf(m_c, mw0), fmaxf(mw1, mw2));
      float f0 = exp2f(m_c - m_tot);
      float fa = exp2f(mw0 - m_tot);
      float fb = exp2f(mw1 - m_tot);
      float fc = exp2f(mw2 - m_tot);
      float l_tot = l_c * f0 + Ll[0][c] * fa + Ll[1][c] * fb + Ll[2][c] * fc;
      Fq[0][c] = f0; Fq[1][c] = fa; Fq[2][c] = fb; Fq[3][c] = fc;
      Linv[c] = 1.0f / l_tot;
    }
    asm volatile("s_waitcnt lgkmcnt(0)" ::: "memory");

    const int h = bh & 15, b = bh >> 4;
    #pragma unroll
    for (int r = 0; r < 4; r++){
      int row = g * 4 + r;
      float f0 = Fq[0][row], fa = Fq[1][row], fb = Fq[2][row], fcq = Fq[3][row];
      float li = Linv[row];
      int q = q0 + row;
      #pragma unroll
      for (int nt = 0; nt < 4; nt++){
        float v = o_acc[nt][r] * f0
                + Mo[0][lane][nt * 4 + r] * fa
                + Mo[1][lane][nt * 4 + r] * fb
                + Mo[2][lane][nt * 4 + r] * fcq;
        Og[(size_t)(b * S_ + q) * D_ + h * HS_ + nt * 16 + c] = f2bf(v * li);
      }
    }
  }
}

extern "C" void kernel_launch(void* const* d_in, const int* in_sizes, int n_in,
                              void* d_out, int out_size, void* d_ws, size_t ws_size,
                              hipStream_t stream)
{
  const float* x    = (const float*)d_in[0];
  const float* Wqkv = (const float*)d_in[1];
  const float* bqkv = (const float*)d_in[2];
  const float* Wout = (const float*)d_in[3];
  const float* bout = (const float*)d_in[4];

  char* ws = (char*)d_ws;
  short* xb     = (short*)(ws);                 //  8 MB [4096][1024] bf16 (reused as O_tok)
  short* Wqkv_t = (short*)(ws + 8388608);       //  6 MB [3072][1024]
  short* Wout_t = (short*)(ws + 14680064);      //  2 MB [1024][1024]
  short* Qg     = (short*)(ws + 16777216);      //  8 MB [32][2048][64]
  short* Kg     = Qg + 4194304;                 //  8 MB
  short* Vg     = Qg + 8388608;                 //  8 MB
  short* Vt     = (short*)(ws + 41943040);      //  8 MB [32][64][2048]
  short* Otok   = xb;                           //  reuse (xb dead after QKV GEMM)

  k_cvt<<<4096, 256, 0, stream>>>(x, xb, TOK * D_ / 4);
  k_tconv<<<dim3(96, 32), 256, 0, stream>>>(Wqkv, Wqkv_t, 1024, 3072);
  k_tconv<<<dim3(32, 32), 256, 0, stream>>>(Wout, Wout_t, 1024, 1024);
  k_gemm<0><<<dim3(32, 24), 256, 0, stream>>>(xb, Wqkv_t, bqkv, (void*)Qg);
  k_vtrans<<<dim3(32, 32), 256, 0, stream>>>(Vg, Vt);
  k_attn<<<dim3(4096), 256, 0, stream>>>(Qg, Kg, Vt, Otok);
  k_gemm<1><<<dim3(32, 8), 256, 0, stream>>>(Otok, Wout_t, bout, d_out);
}